// Round 4
// baseline (110.896 us; speedup 1.0000x reference)
//
#include <hip/hip_runtime.h>
#include <math.h>
#include <utility>

// Levinson-Durbin, 4 lanes per batch (blocked split of the reversed-vector form).
// Round-4 change: ALL private-array indices are std::integral_constant template
// constants, so SROA promotes rr/aa/bb to VGPRs (round 3 left them in scratch:
// VGPR_Count=32 despite ~60 live floats).

constexpr int M    = 64;
constexpr int EL   = M + 1;        // 65 floats per row
constexpr int LPB  = 4;            // lanes per batch
constexpr int NJ   = M / LPB;      // 16 elements per lane
constexpr int BT   = 256;          // threads per block
constexpr int ROWS = BT / LPB;     // 64 batches per block

template <class F, size_t... I>
__device__ __forceinline__ void unroll_impl(F&& f, std::index_sequence<I...>) {
  (f(std::integral_constant<int, (int)I>{}), ...);
}
template <size_t N, class F>
__device__ __forceinline__ void unroll(F&& f) {
  unroll_impl(static_cast<F&&>(f), std::make_index_sequence<N>{});
}

__global__ __launch_bounds__(BT, 4) void levinson_kernel(const float* __restrict__ rin,
                                                         float* __restrict__ out,
                                                         int B) {
  __shared__ float smem[ROWS * EL];   // 16,640 B
  const int tid = threadIdx.x;
  const int b0  = blockIdx.x * ROWS;
  if (b0 >= B) return;
  const int nf  = ROWS * EL;          // B=65536 -> 1024 full blocks, exact
  const size_t base = (size_t)b0 * EL;

  // ---- coalesced stage-in: global float4 -> LDS ----
  {
    const int n4 = nf >> 2;           // 1040, exact
    const float4* in4 = reinterpret_cast<const float4*>(rin + base);  // 16B aligned
    float4* s4 = reinterpret_cast<float4*>(smem);
    for (int i = tid; i < n4; i += BT) s4[i] = in4[i];
  }
  __syncthreads();

  const int row = tid >> 2;           // local batch
  const int s   = tid & 3;            // sub-lane within batch
  const float* rrow = &smem[row * EL];
  const int rbase = 16 * s + 1;

  float rr[NJ], aa[NJ], bb[NJ];
  unroll<NJ>([&](auto j) { rr[j] = rrow[rbase + j]; });   // stride-65 rows: 2-way (free)
  unroll<NJ>([&](auto j) { aa[j] = 0.f; bb[j] = 0.f; });
  if (s == 0) bb[0] = 1.f;            // b_0 = delta_0
  float E = rrow[0];

#pragma unroll 1
  for (int m = 1; m <= M; ++m) {
    // partial dot: acc = sum_j bb[j]*rr[j], 4 accumulators for ILP
    float p0 = 0.f, p1 = 0.f, p2 = 0.f, p3 = 0.f;
    unroll<NJ / 4>([&](auto q) {
      p0 = fmaf(bb[4 * q + 0], rr[4 * q + 0], p0);
      p1 = fmaf(bb[4 * q + 1], rr[4 * q + 1], p1);
      p2 = fmaf(bb[4 * q + 2], rr[4 * q + 2], p2);
      p3 = fmaf(bb[4 * q + 3], rr[4 * q + 3], p3);
    });
    float acc = (p0 + p1) + (p2 + p3);
    acc += __shfl_xor(acc, 1);        // 4-lane group butterfly:
    acc += __shfl_xor(acc, 2);        // all 4 lanes hold the full sum
    const float k = -acc / E;         // IEEE divide (precision), redundant per lane

    // previous lane's trailing elements (old values), before any overwrite
    const float pbb = __shfl_up(bb[NJ - 1], 1);
    const float paa = __shfl_up(aa[NJ - 1], 1);

    // descending joint update; reads of [j-1] happen before step j-1 writes them
    unroll<NJ - 1>([&](auto t) {
      constexpr int j = NJ - 1 - t;
      const float tb = bb[j];
      bb[j] = fmaf(k, aa[j - 1], bb[j - 1]);
      aa[j] = fmaf(k, tb, aa[j]);
    });
    {
      const float tb = bb[0];
      bb[0] = (s == 0) ? k : fmaf(k, paa, pbb);  // Bb[0]=k; Bb[16s]=Bb_old[16s-1]+k*A_old[16s]
      aa[0] = fmaf(k, tb, aa[0]);
    }
    E = fmaf(-k * k, E, E);           // E *= (1 - k^2)
  }

  __syncthreads();                    // input consumed; reuse smem for output

  {
    float* orow = &smem[row * EL];
    if (s == 0) orow[0] = sqrtf(E);
    unroll<NJ>([&](auto j) { orow[rbase + j] = aa[j]; });
  }
  __syncthreads();

  // ---- coalesced stage-out: LDS -> global float4 ----
  {
    const int n4 = nf >> 2;
    const float4* s4 = reinterpret_cast<const float4*>(smem);
    float4* out4 = reinterpret_cast<float4*>(out + base);
    for (int i = tid; i < n4; i += BT) out4[i] = s4[i];
  }
}

extern "C" void kernel_launch(void* const* d_in, const int* in_sizes, int n_in,
                              void* d_out, int out_size, void* d_ws, size_t ws_size,
                              hipStream_t stream) {
  const float* r = (const float*)d_in[0];
  float* out = (float*)d_out;
  const int B = in_sizes[0] / EL;            // 65536
  const int blocks = (B + ROWS - 1) / ROWS;  // 1024
  levinson_kernel<<<blocks, BT, 0, stream>>>(r, out, B);
}

// Round 5
// 107.828 us; speedup vs baseline: 1.0284x; 1.0284x over previous
//
#include <hip/hip_runtime.h>
#include <math.h>

// Levinson-Durbin, 4 lanes per batch. Round-5 change: per-thread state lives in
// ext_vector_type(16) SSA vectors (NO arrays, NO lambdas, literal element
// indices only) so nothing can fall to scratch. Rounds 3/4 kept the state in
// scratch (VGPR_Count 32/36 for ~60 live floats) because lambda captures made
// the array allocas escape SROA.
//
// Math (identical to rounds 2-4, all passed):
//   lane s of a 4-lane group, j = 0..15:
//     rr[j] = r[16s+1+j], aa[j] = A[16s+1+j], bb[j] = Bb[16s+j]
//   acc = sum bb*rr (4-lane butterfly); k = -acc/E
//   aa[j] = fma(k, bb_old[j], aa[j])                       (index-aligned)
//   bb[j] = fma(k, aas[j], bbs[j]),  aas/bbs = shift-by-1 w/ prev-lane elem0
//   bb[0] = k on s==0;  E *= (1-k^2);  K = sqrt(E)

constexpr int M    = 64;
constexpr int EL   = M + 1;        // 65 floats per row
constexpr int LPB  = 4;            // lanes per batch
constexpr int BT   = 256;          // threads per block
constexpr int ROWS = BT / LPB;     // 64 batches per block

typedef float vf16 __attribute__((ext_vector_type(16)));

#define REP16(X) X(0) X(1) X(2) X(3) X(4) X(5) X(6) X(7) \
                 X(8) X(9) X(10) X(11) X(12) X(13) X(14) X(15)

__global__ __launch_bounds__(BT, 4) void levinson_kernel(const float* __restrict__ rin,
                                                         float* __restrict__ out) {
  __shared__ float smem[ROWS * EL];   // 16,640 B
  const int tid = threadIdx.x;
  const int b0  = blockIdx.x * ROWS;
  const int nf  = ROWS * EL;          // 4160 floats; grid exact for B=65536
  const size_t base = (size_t)b0 * EL;

  // ---- coalesced stage-in: global float4 -> LDS ----
  {
    const int n4 = nf >> 2;           // 1040, exact
    const float4* in4 = reinterpret_cast<const float4*>(rin + base);  // 16B aligned
    float4* s4 = reinterpret_cast<float4*>(smem);
    for (int i = tid; i < n4; i += BT) s4[i] = in4[i];
  }
  __syncthreads();

  const int row = tid >> 2;           // local batch
  const int s   = tid & 3;            // sub-lane within batch
  const float* rrow = &smem[row * EL];
  const int rbase = 16 * s + 1;

  vf16 rr, aa = {}, bb = {};
#define LDRR(i) rr[i] = rrow[rbase + i];
  REP16(LDRR)
#undef LDRR
  if (s == 0) bb[0] = 1.f;            // b_0 = delta_0
  float E = rrow[0];

#pragma unroll 2
  for (int m = 1; m <= M; ++m) {
    // prev-lane trailing elements (old values) — issue DS early, overlaps dot
    const float pbb = __shfl_up(bb[15], 1);
    const float paa = __shfl_up(aa[15], 1);

    // partial dot: 4 independent fma chains
    float p0 = bb[0] * rr[0], p1 = bb[1] * rr[1];
    float p2 = bb[2] * rr[2], p3 = bb[3] * rr[3];
    p0 = fmaf(bb[4],  rr[4],  p0); p1 = fmaf(bb[5],  rr[5],  p1);
    p2 = fmaf(bb[6],  rr[6],  p2); p3 = fmaf(bb[7],  rr[7],  p3);
    p0 = fmaf(bb[8],  rr[8],  p0); p1 = fmaf(bb[9],  rr[9],  p1);
    p2 = fmaf(bb[10], rr[10], p2); p3 = fmaf(bb[11], rr[11], p3);
    p0 = fmaf(bb[12], rr[12], p0); p1 = fmaf(bb[13], rr[13], p1);
    p2 = fmaf(bb[14], rr[14], p2); p3 = fmaf(bb[15], rr[15], p3);
    float acc = (p0 + p1) + (p2 + p3);
    acc += __shfl_xor(acc, 1);        // 4-lane butterfly: all lanes get full sum
    acc += __shfl_xor(acc, 2);
    const float k = -acc / E;         // IEEE divide, redundant per lane

    // shifted snapshots (SSA values — no ordering hazard)
    vf16 bbs = __builtin_shufflevector(bb, bb, 15, 0, 1, 2, 3, 4, 5, 6, 7,
                                       8, 9, 10, 11, 12, 13, 14);
    vf16 aas = __builtin_shufflevector(aa, aa, 15, 0, 1, 2, 3, 4, 5, 6, 7,
                                       8, 9, 10, 11, 12, 13, 14);
    bbs[0] = pbb;
    aas[0] = paa;

#define UPD(i) { const float na = fmaf(k, bb[i], aa[i]);       \
                 const float nb = fmaf(k, aas[i], bbs[i]);     \
                 aa[i] = na; bb[i] = nb; }
    REP16(UPD)
#undef UPD
    if (s == 0) bb[0] = k;            // Bb[0] = k
    E = fmaf(-k * k, E, E);           // E *= (1 - k^2)
  }

  __syncthreads();                    // input consumed; reuse smem for output

  {
    float* orow = &smem[row * EL];
    if (s == 0) orow[0] = sqrtf(E);
#define STA(i) orow[rbase + i] = aa[i];
    REP16(STA)
#undef STA
  }
  __syncthreads();

  // ---- coalesced stage-out: LDS -> global float4 ----
  {
    const int n4 = nf >> 2;
    const float4* s4 = reinterpret_cast<const float4*>(smem);
    float4* out4 = reinterpret_cast<float4*>(out + base);
    for (int i = tid; i < n4; i += BT) out4[i] = s4[i];
  }
}

extern "C" void kernel_launch(void* const* d_in, const int* in_sizes, int n_in,
                              void* d_out, int out_size, void* d_ws, size_t ws_size,
                              hipStream_t stream) {
  const float* r = (const float*)d_in[0];
  float* out = (float*)d_out;
  const int B = in_sizes[0] / EL;            // 65536
  const int blocks = B / ROWS;               // 1024, exact
  levinson_kernel<<<blocks, BT, 0, stream>>>(r, out);
}